// Round 3
// baseline (338.459 us; speedup 1.0000x reference)
//
#include <hip/hip_runtime.h>

// B=4, T=4096, D=1024. Inputs/outputs fp32 (reference is pure float32).
// GEMM compute in bf16 MFMA; scan in fp32 with bf16 intermediates.
#define D_DIM 1024
#define B_DIM 4
#define T_DIM 4096
#define M_DIM (B_DIM * T_DIM)   // 16384 rows
#define CHUNK 32
#define NCHUNK (T_DIM / CHUNK)  // 128

typedef unsigned short u16;
typedef __attribute__((ext_vector_type(8))) unsigned short us8;
typedef __attribute__((ext_vector_type(8))) __bf16 bf16x8;
typedef __attribute__((ext_vector_type(4))) float f32x4;

__device__ __forceinline__ float bf2f(u16 u) {
    union { unsigned int i; float f; } v;
    v.i = ((unsigned int)u) << 16;
    return v.f;
}
__device__ __forceinline__ u16 f2bf(float f) {
    union { float f; unsigned int i; } v;
    v.f = f;
    unsigned int u = v.i;
    unsigned int r = (u + 0x7fffu + ((u >> 16) & 1u)) >> 16;
    return (u16)r;
}
__device__ __forceinline__ float fast_tanh(float v) {
    float e = __expf(2.f * v);          // v>>0: e=inf -> 1-0=1 ; v<<0: e=0 -> -1
    return 1.f - 2.f / (e + 1.f);
}

// ---------------- fp32 -> bf16 weight convert (1M elements per call) ----------------
__global__ __launch_bounds__(256) void conv_kernel(const float* __restrict__ src,
                                                   u16* __restrict__ dst) {
    int i = blockIdx.x * 256 + threadIdx.x;   // i in [0, 262144)
    float4 v = ((const float4*)src)[i];
    ushort4 o;
    o.x = f2bf(v.x); o.y = f2bf(v.y); o.z = f2bf(v.z); o.w = f2bf(v.w);
    ((ushort4*)dst)[i] = o;
}

// ---------------- LayerNorm: one block (256 thr) per row of 1024; fp32 in, bf16 out ----
__global__ __launch_bounds__(256) void ln_kernel(const float* __restrict__ x,
                                                 const float* __restrict__ w,
                                                 const float* __restrict__ b,
                                                 u16* __restrict__ xn) {
    __shared__ float red[8];
    int row = blockIdx.x;
    int tid = threadIdx.x;
    float4 v = ((const float4*)(x + (size_t)row * D_DIM))[tid];
    float s  = v.x + v.y + v.z + v.w;
    float s2 = v.x * v.x + v.y * v.y + v.z * v.z + v.w * v.w;
    #pragma unroll
    for (int o = 32; o > 0; o >>= 1) {
        s  += __shfl_xor(s, o, 64);
        s2 += __shfl_xor(s2, o, 64);
    }
    int wave = tid >> 6, lane = tid & 63;
    if (lane == 0) { red[wave] = s; red[wave + 4] = s2; }
    __syncthreads();
    if (tid == 0) {
        float ts  = red[0] + red[1] + red[2] + red[3];
        float ts2 = red[4] + red[5] + red[6] + red[7];
        float mu  = ts * (1.0f / D_DIM);
        float var = ts2 * (1.0f / D_DIM) - mu * mu;
        red[0] = mu;
        red[1] = rsqrtf(var + 1e-5f);
    }
    __syncthreads();
    float mu = red[0], rs = red[1];
    float4 wv = ((const float4*)w)[tid];
    float4 bv = ((const float4*)b)[tid];
    ushort4 o;
    o.x = f2bf((v.x - mu) * rs * wv.x + bv.x);
    o.y = f2bf((v.y - mu) * rs * wv.y + bv.y);
    o.z = f2bf((v.z - mu) * rs * wv.z + bv.z);
    o.w = f2bf((v.w - mu) * rs * wv.w + bv.w);
    ((ushort4*)(xn + (size_t)row * D_DIM))[tid] = o;
}

// ---------------- GEMM: C[M][N] = A[M][K] * Bm[N][K]^T, 128x128 tile, K-step 32 (bf16 MFMA)
// EPI=0: z = acc + bias[col] + alpha_bias; alpha = sigmoid(z); out_bf = bf16(log(alpha+1e-8))
// EPI=1: g = tanh(acc + bias[col]); out_f = 0.05*g + resid[idx]   (fp32)
template <int EPI>
__global__ __launch_bounds__(256) void gemm_kernel(const u16* __restrict__ A,
                                                   const u16* __restrict__ Bm,
                                                   const float* __restrict__ bias,
                                                   const float* __restrict__ resid,
                                                   const float* __restrict__ sc0,
                                                   u16* __restrict__ out_bf,
                                                   float* __restrict__ out_f) {
    __shared__ __align__(16) u16 lds_a[128 * 32];
    __shared__ __align__(16) u16 lds_b[128 * 32];
    int tid  = threadIdx.x;
    int wave = tid >> 6, lane = tid & 63;
    int tile_n = blockIdx.x * 128;
    int tile_m = blockIdx.y * 128;
    int wr = wave >> 1, wc = wave & 1;  // wave computes 64x64 at (wr*64, wc*64)

    f32x4 acc[4][4] = {};

    int srow = wave * 32 + (lane >> 2);
    int scol = (lane & 3) * 8;
    const u16* ga0 = A  + (size_t)(tile_m + srow) * D_DIM + scol;
    const u16* ga1 = ga0 + 16 * D_DIM;
    const u16* gb0 = Bm + (size_t)(tile_n + srow) * D_DIM + scol;
    const u16* gb1 = gb0 + 16 * D_DIM;
    u16* la0 = &lds_a[srow * 32 + scol];
    u16* la1 = &lds_a[(srow + 16) * 32 + scol];
    u16* lb0 = &lds_b[srow * 32 + scol];
    u16* lb1 = &lds_b[(srow + 16) * 32 + scol];

    for (int k0 = 0; k0 < D_DIM; k0 += 32) {
        us8 va0 = *(const us8*)(ga0 + k0);
        us8 va1 = *(const us8*)(ga1 + k0);
        us8 vb0 = *(const us8*)(gb0 + k0);
        us8 vb1 = *(const us8*)(gb1 + k0);
        __syncthreads();               // previous iteration's LDS reads complete
        *(us8*)la0 = va0;
        *(us8*)la1 = va1;
        *(us8*)lb0 = vb0;
        *(us8*)lb1 = vb1;
        __syncthreads();               // tile visible to all waves

        // A-operand layout: lane holds A[m = lane&15][k = (lane>>4)*8 + j]
        bf16x8 af[4], bfr[4];
        #pragma unroll
        for (int mi = 0; mi < 4; mi++) {
            int m = wr * 64 + mi * 16 + (lane & 15);
            af[mi] = *(const bf16x8*)&lds_a[m * 32 + (lane >> 4) * 8];
        }
        #pragma unroll
        for (int ni = 0; ni < 4; ni++) {
            int n = wc * 64 + ni * 16 + (lane & 15);
            bfr[ni] = *(const bf16x8*)&lds_b[n * 32 + (lane >> 4) * 8];
        }
        #pragma unroll
        for (int mi = 0; mi < 4; mi++)
            #pragma unroll
            for (int ni = 0; ni < 4; ni++)
                acc[mi][ni] = __builtin_amdgcn_mfma_f32_16x16x32_bf16(
                    af[mi], bfr[ni], acc[mi][ni], 0, 0, 0);
    }

    // C/D layout: col = lane&15, row = (lane>>4)*4 + r   [m89-verified]
    if constexpr (EPI == 0) {
        float abv = sc0[0];
        #pragma unroll
        for (int mi = 0; mi < 4; mi++) {
            #pragma unroll
            for (int r = 0; r < 4; r++) {
                int row = tile_m + wr * 64 + mi * 16 + (lane >> 4) * 4 + r;
                #pragma unroll
                for (int ni = 0; ni < 4; ni++) {
                    int col = tile_n + wc * 64 + ni * 16 + (lane & 15);
                    size_t idx = (size_t)row * D_DIM + col;
                    float z = acc[mi][ni][r] + bias[col] + abv;
                    float alpha = 1.f / (1.f + __expf(-z));
                    out_bf[idx] = f2bf(__logf(alpha + 1e-8f));
                }
            }
        }
    } else {
        #pragma unroll
        for (int mi = 0; mi < 4; mi++) {
            #pragma unroll
            for (int r = 0; r < 4; r++) {
                int row = tile_m + wr * 64 + mi * 16 + (lane >> 4) * 4 + r;
                #pragma unroll
                for (int ni = 0; ni < 4; ni++) {
                    int col = tile_n + wc * 64 + ni * 16 + (lane & 15);
                    size_t idx = (size_t)row * D_DIM + col;
                    float g = fast_tanh(acc[mi][ni][r] + bias[col]);
                    out_f[idx] = 0.05f * g + resid[idx];
                }
            }
        }
    }
}

// ---------------- chunked scan over T per (b,d) column ----------------
// la holds bf16 log(alpha+1e-8); (1-alpha) recovered as -expm1(la).
// pass 1: per chunk of 32: S=sum(la), Ml=max local prefix, Tb=sum bx*exp(p-Ml)
__global__ __launch_bounds__(256) void scan_chunk(const u16* __restrict__ la,
                                                  const u16* __restrict__ xn,
                                                  const float* __restrict__ bs,
                                                  float* __restrict__ S,
                                                  float* __restrict__ Ml,
                                                  float* __restrict__ Tb) {
    int bc = blockIdx.x;  // b*NCHUNK + c
    int b = bc >> 7, c = bc & (NCHUNK - 1);
    int d = blockIdx.y * 256 + threadIdx.x;
    float bsv = bs[0];
    size_t base = ((size_t)(b * T_DIM + c * CHUNK)) * D_DIM + d;
    float p[CHUNK];
    float run = 0.f, mx = -3.4e38f;
    #pragma unroll
    for (int t = 0; t < CHUNK; t++) {
        run += bf2f(la[base + (size_t)t * D_DIM]);
        p[t] = run;
        mx = fmaxf(mx, run);
    }
    float tb = 0.f;
    #pragma unroll
    for (int t = 0; t < CHUNK; t++) {
        size_t idx = base + (size_t)t * D_DIM;
        float lav = bf2f(la[idx]);
        float bx = bsv * (-expm1f(lav)) * bf2f(xn[idx]);
        tb += bx * __expf(p[t] - mx);
    }
    size_t ci = ((size_t)(b * NCHUNK + c)) * D_DIM + d;
    S[ci] = run; Ml[ci] = mx; Tb[ci] = tb;
}

// pass 2: sequential over 128 chunks per (b,d): global max m, exclusive offsets
__global__ __launch_bounds__(256) void scan_combine(const float* __restrict__ S,
                                                    const float* __restrict__ Ml,
                                                    const float* __restrict__ Tb,
                                                    float* __restrict__ Of,
                                                    float* __restrict__ SSp) {
    int b = blockIdx.x >> 2;
    int d = (blockIdx.x & 3) * 256 + threadIdx.x;
    float O = 0.f, m = -3.4e38f;
    for (int c = 0; c < NCHUNK; c++) {
        size_t ci = ((size_t)(b * NCHUNK + c)) * D_DIM + d;
        m = fmaxf(m, O + Ml[ci]);
        O += S[ci];
    }
    float O2 = 0.f, ss = 0.f;
    for (int c = 0; c < NCHUNK; c++) {
        size_t ci = ((size_t)(b * NCHUNK + c)) * D_DIM + d;
        Of[ci] = O2 - m;
        SSp[ci] = ss;
        ss += __expf(O2 + Ml[ci] - m) * Tb[ci];
        O2 += S[ci];
    }
}

// pass 3: scale=exp(Of+p), s_star=SSp+local cumsum, out=s_star/(scale+1e-8) as bf16.
// osc aliases xn: la/xn reads at idx happen before osc write at idx, same thread.
__global__ __launch_bounds__(256) void scan_final(const u16* __restrict__ la,
                                                  const u16* __restrict__ xn,
                                                  const float* __restrict__ bs,
                                                  const float* __restrict__ Of,
                                                  const float* __restrict__ SSp,
                                                  u16* __restrict__ osc) {
    int bc = blockIdx.x;
    int b = bc >> 7, c = bc & (NCHUNK - 1);
    int d = blockIdx.y * 256 + threadIdx.x;
    float bsv = bs[0];
    size_t base = ((size_t)(b * T_DIM + c * CHUNK)) * D_DIM + d;
    size_t ci = ((size_t)(b * NCHUNK + c)) * D_DIM + d;
    float ofs = Of[ci], ss = SSp[ci], p = 0.f;
    #pragma unroll
    for (int t = 0; t < CHUNK; t++) {
        size_t idx = base + (size_t)t * D_DIM;
        float lav = bf2f(la[idx]);
        p += lav;
        float scv = __expf(ofs + p);
        float bx = bsv * (-expm1f(lav)) * bf2f(xn[idx]);
        ss += bx * scv;
        osc[idx] = f2bf(ss / (scv + 1e-8f));
    }
}

extern "C" void kernel_launch(void* const* d_in, const int* in_sizes, int n_in,
                              void* d_out, int out_size, void* d_ws, size_t ws_size,
                              hipStream_t stream) {
    const float* x   = (const float*)d_in[0];
    const float* lnw = (const float*)d_in[1];
    const float* lnb = (const float*)d_in[2];
    const float* Wf  = (const float*)d_in[3];
    const float* bf_ = (const float*)d_in[4];
    const float* Wr  = (const float*)d_in[5];
    const float* br  = (const float*)d_in[6];
    const float* ab  = (const float*)d_in[7];
    const float* bs  = (const float*)d_in[8];
    float* out = (float*)d_out;

    // workspace (78 MB):
    //   xn  : [ 0,32MB) bf16 layernorm out; later overwritten in-place by scan output
    //   la  : [32,64MB) bf16 log(alpha+1e-8) from GEMM1
    //   Wfc : [64,66MB) bf16 Wf     Wrc : [66,68MB) bf16 Wr
    //   S,Ml,Tb,Of,SSp : 5 x 2MB fp32 at [68,78MB)
    char* w = (char*)d_ws;
    u16* xn  = (u16*)w;
    u16* la  = (u16*)(w + (size_t)33554432);
    u16* Wfc = (u16*)(w + (size_t)67108864);
    u16* Wrc = (u16*)(w + (size_t)69206016);
    float* S   = (float*)(w + (size_t)71303168);
    float* Ml  = S  + 524288;
    float* Tb  = Ml + 524288;
    float* Of  = Tb + 524288;
    float* SSp = Of + 524288;
    u16* osc = xn;

    conv_kernel<<<dim3(1024), dim3(256), 0, stream>>>(Wf, Wfc);
    conv_kernel<<<dim3(1024), dim3(256), 0, stream>>>(Wr, Wrc);
    ln_kernel<<<dim3(M_DIM), dim3(256), 0, stream>>>(x, lnw, lnb, xn);
    gemm_kernel<0><<<dim3(D_DIM / 128, M_DIM / 128), dim3(256), 0, stream>>>(
        xn, Wfc, bf_, nullptr, ab, la, nullptr);
    scan_chunk<<<dim3(B_DIM * NCHUNK, 4), dim3(256), 0, stream>>>(la, xn, bs, S, Ml, Tb);
    scan_combine<<<dim3(B_DIM * 4), dim3(256), 0, stream>>>(S, Ml, Tb, Of, SSp);
    scan_final<<<dim3(B_DIM * NCHUNK, 4), dim3(256), 0, stream>>>(la, xn, bs, Of, SSp, osc);
    gemm_kernel<1><<<dim3(D_DIM / 128, M_DIM / 128), dim3(256), 0, stream>>>(
        osc, Wrc, br, x, nullptr, nullptr, out);
}

// Round 4
// 307.630 us; speedup vs baseline: 1.1002x; 1.1002x over previous
//
#include <hip/hip_runtime.h>

// B=4, T=4096, D=1024. Inputs/outputs fp32 (reference is pure float32).
// GEMM compute in bf16 MFMA; scan in fp32 with bf16 intermediates.
#define D_DIM 1024
#define B_DIM 4
#define T_DIM 4096
#define M_DIM (B_DIM * T_DIM)   // 16384 rows
#define CHUNK 32
#define NCHUNK (T_DIM / CHUNK)  // 128
#define SEG (NCHUNK / 4)        // 32 chunks per wave in combine

typedef unsigned short u16;
typedef __attribute__((ext_vector_type(8))) unsigned short us8;
typedef __attribute__((ext_vector_type(8))) __bf16 bf16x8;
typedef __attribute__((ext_vector_type(4))) float f32x4;

__device__ __forceinline__ float bf2f(u16 u) {
    union { unsigned int i; float f; } v;
    v.i = ((unsigned int)u) << 16;
    return v.f;
}
__device__ __forceinline__ u16 f2bf(float f) {
    union { float f; unsigned int i; } v;
    v.f = f;
    unsigned int u = v.i;
    unsigned int r = (u + 0x7fffu + ((u >> 16) & 1u)) >> 16;
    return (u16)r;
}
__device__ __forceinline__ float fast_tanh(float v) {
    float e = __expf(2.f * v);          // v>>0: e=inf -> 1 ; v<<0: e=0 -> -1
    return 1.f - 2.f / (e + 1.f);
}

// async global->LDS, 16B/lane; LDS dest = wave-uniform base + lane*16 (m97-verified)
#define GLOAD16(g, l)                                                   \
    __builtin_amdgcn_global_load_lds(                                   \
        (const __attribute__((address_space(1))) void*)(g),             \
        (__attribute__((address_space(3))) void*)(l), 16, 0, 0)

// ---------------- fp32 -> bf16 weight convert, both weights in one launch ----------------
__global__ __launch_bounds__(256) void conv2_kernel(const float* __restrict__ a,
                                                    const float* __restrict__ b,
                                                    u16* __restrict__ da,
                                                    u16* __restrict__ db) {
    int i = blockIdx.x * 256 + threadIdx.x;   // i in [0, 524288): 2 x 262144 float4s
    const float* s = (i < 262144) ? a : b;
    u16* dp = (i < 262144) ? da : db;
    int j = i & 262143;
    float4 v = ((const float4*)s)[j];
    ushort4 o;
    o.x = f2bf(v.x); o.y = f2bf(v.y); o.z = f2bf(v.z); o.w = f2bf(v.w);
    ((ushort4*)dp)[j] = o;
}

// ---------------- LayerNorm: one block (256 thr) per row of 1024; fp32 in, bf16 out ----
__global__ __launch_bounds__(256) void ln_kernel(const float* __restrict__ x,
                                                 const float* __restrict__ w,
                                                 const float* __restrict__ b,
                                                 u16* __restrict__ xn) {
    __shared__ float red[8];
    int row = blockIdx.x;
    int tid = threadIdx.x;
    float4 v = ((const float4*)(x + (size_t)row * D_DIM))[tid];
    float s  = v.x + v.y + v.z + v.w;
    float s2 = v.x * v.x + v.y * v.y + v.z * v.z + v.w * v.w;
    #pragma unroll
    for (int o = 32; o > 0; o >>= 1) {
        s  += __shfl_xor(s, o, 64);
        s2 += __shfl_xor(s2, o, 64);
    }
    int wave = tid >> 6, lane = tid & 63;
    if (lane == 0) { red[wave] = s; red[wave + 4] = s2; }
    __syncthreads();
    if (tid == 0) {
        float ts  = red[0] + red[1] + red[2] + red[3];
        float ts2 = red[4] + red[5] + red[6] + red[7];
        float mu  = ts * (1.0f / D_DIM);
        float var = ts2 * (1.0f / D_DIM) - mu * mu;
        red[0] = mu;
        red[1] = rsqrtf(var + 1e-5f);
    }
    __syncthreads();
    float mu = red[0], rs = red[1];
    float4 wv = ((const float4*)w)[tid];
    float4 bv = ((const float4*)b)[tid];
    ushort4 o;
    o.x = f2bf((v.x - mu) * rs * wv.x + bv.x);
    o.y = f2bf((v.y - mu) * rs * wv.y + bv.y);
    o.z = f2bf((v.z - mu) * rs * wv.z + bv.z);
    o.w = f2bf((v.w - mu) * rs * wv.w + bv.w);
    ((ushort4*)(xn + (size_t)row * D_DIM))[tid] = o;
}

// ---------------- GEMM: C[M][N] = A[M][K] * Bm[N][K]^T, 128x128 tile, K-step 32 (bf16 MFMA)
// Staging via global_load_lds width=16 (m97 structure).
// EPI=0: z = acc + bias[col] + alpha_bias; alpha = sigmoid(z); out_bf = bf16(log(alpha+1e-8))
// EPI=1: g = tanh(acc + bias[col]); out_f = 0.05*g + resid[idx]   (fp32)
template <int EPI>
__global__ __launch_bounds__(256) void gemm_kernel(const u16* __restrict__ A,
                                                   const u16* __restrict__ Bm,
                                                   const float* __restrict__ bias,
                                                   const float* __restrict__ resid,
                                                   const float* __restrict__ sc0,
                                                   u16* __restrict__ out_bf,
                                                   float* __restrict__ out_f) {
    __shared__ __align__(16) u16 lds_a[128 * 32];
    __shared__ __align__(16) u16 lds_b[128 * 32];
    int tid  = threadIdx.x;
    int wave = tid >> 6, lane = tid & 63;
    int tile_n = blockIdx.x * 128;
    int tile_m = blockIdx.y * 128;
    int wr = wave >> 1, wc = wave & 1;  // wave computes 64x64 at (wr*64, wc*64)

    f32x4 acc[4][4] = {};

    // staging: wave w covers rows [w*32, w*32+32); lane i -> row w*32+(i>>2), cols (i&3)*8
    int srow = wave * 32 + (lane >> 2);
    int scol = (lane & 3) * 8;
    const u16* ga0 = A  + (size_t)(tile_m + srow) * D_DIM + scol;
    const u16* ga1 = ga0 + 16 * D_DIM;
    const u16* gb0 = Bm + (size_t)(tile_n + srow) * D_DIM + scol;
    const u16* gb1 = gb0 + 16 * D_DIM;
    u16* la0 = &lds_a[(wave * 32) * 32];        // wave-uniform LDS bases
    u16* la1 = &lds_a[(wave * 32 + 16) * 32];
    u16* lb0 = &lds_b[(wave * 32) * 32];
    u16* lb1 = &lds_b[(wave * 32 + 16) * 32];

    for (int k0 = 0; k0 < D_DIM; k0 += 32) {
        GLOAD16(ga0 + k0, la0);
        GLOAD16(ga1 + k0, la1);
        GLOAD16(gb0 + k0, lb0);
        GLOAD16(gb1 + k0, lb1);
        __syncthreads();               // vmcnt(0) drain -> tile visible

        // A-operand layout: lane holds A[m = lane&15][k = (lane>>4)*8 + j]
        bf16x8 af[4], bfr[4];
        #pragma unroll
        for (int mi = 0; mi < 4; mi++) {
            int m = wr * 64 + mi * 16 + (lane & 15);
            af[mi] = *(const bf16x8*)&lds_a[m * 32 + (lane >> 4) * 8];
        }
        #pragma unroll
        for (int ni = 0; ni < 4; ni++) {
            int n = wc * 64 + ni * 16 + (lane & 15);
            bfr[ni] = *(const bf16x8*)&lds_b[n * 32 + (lane >> 4) * 8];
        }
        #pragma unroll
        for (int mi = 0; mi < 4; mi++)
            #pragma unroll
            for (int ni = 0; ni < 4; ni++)
                acc[mi][ni] = __builtin_amdgcn_mfma_f32_16x16x32_bf16(
                    af[mi], bfr[ni], acc[mi][ni], 0, 0, 0);
        __syncthreads();               // ds_reads done before next overwrite
    }

    // C/D layout: col = lane&15, row = (lane>>4)*4 + r   [m89-verified]
    if constexpr (EPI == 0) {
        float abv = sc0[0];
        #pragma unroll
        for (int mi = 0; mi < 4; mi++) {
            #pragma unroll
            for (int r = 0; r < 4; r++) {
                int row = tile_m + wr * 64 + mi * 16 + (lane >> 4) * 4 + r;
                #pragma unroll
                for (int ni = 0; ni < 4; ni++) {
                    int col = tile_n + wc * 64 + ni * 16 + (lane & 15);
                    size_t idx = (size_t)row * D_DIM + col;
                    float z = acc[mi][ni][r] + bias[col] + abv;
                    float alpha = 1.f / (1.f + __expf(-z));
                    out_bf[idx] = f2bf(__logf(alpha + 1e-8f));
                }
            }
        }
    } else {
        #pragma unroll
        for (int mi = 0; mi < 4; mi++) {
            #pragma unroll
            for (int r = 0; r < 4; r++) {
                int row = tile_m + wr * 64 + mi * 16 + (lane >> 4) * 4 + r;
                #pragma unroll
                for (int ni = 0; ni < 4; ni++) {
                    int col = tile_n + wc * 64 + ni * 16 + (lane & 15);
                    size_t idx = (size_t)row * D_DIM + col;
                    float g = fast_tanh(acc[mi][ni][r] + bias[col]);
                    out_f[idx] = 0.05f * g + resid[idx];
                }
            }
        }
    }
}

// ---------------- chunked scan over T per (b,d) column ----------------
// la holds bf16 log(alpha+1e-8); (1-alpha) recovered as -expm1(la).
// pass 1: per chunk of 32: S=sum(la), Ml=max local prefix, Tb=sum bx*exp(p-Ml)
__global__ __launch_bounds__(256) void scan_chunk(const u16* __restrict__ la,
                                                  const u16* __restrict__ xn,
                                                  const float* __restrict__ bs,
                                                  float* __restrict__ S,
                                                  float* __restrict__ Ml,
                                                  float* __restrict__ Tb) {
    int bc = blockIdx.x;  // b*NCHUNK + c
    int b = bc >> 7, c = bc & (NCHUNK - 1);
    int d = blockIdx.y * 256 + threadIdx.x;
    float bsv = bs[0];
    size_t base = ((size_t)(b * T_DIM + c * CHUNK)) * D_DIM + d;
    float p[CHUNK];
    float run = 0.f, mx = -3.4e38f;
    #pragma unroll
    for (int t = 0; t < CHUNK; t++) {
        run += bf2f(la[base + (size_t)t * D_DIM]);
        p[t] = run;
        mx = fmaxf(mx, run);
    }
    float tb = 0.f;
    #pragma unroll
    for (int t = 0; t < CHUNK; t++) {
        size_t idx = base + (size_t)t * D_DIM;
        float lav = bf2f(la[idx]);
        float bx = bsv * (-expm1f(lav)) * bf2f(xn[idx]);
        tb += bx * __expf(p[t] - mx);
    }
    size_t ci = ((size_t)(b * NCHUNK + c)) * D_DIM + d;
    S[ci] = run; Ml[ci] = mx; Tb[ci] = tb;
}

// pass 2 (hierarchical): block = (b, 64 d-columns); 4 waves x 32 chunks each.
// Stage1: per-wave serial (S,M) combine. Stage2: in-register 4-way scan via LDS.
// Stage3: back-substitute: Of, per-chunk w with local exclusive sums. Stage4/5: SSp.
__global__ __launch_bounds__(256) void scan_combine(const float* __restrict__ S,
                                                    const float* __restrict__ Ml,
                                                    const float* __restrict__ Tb,
                                                    float* __restrict__ Of,
                                                    float* __restrict__ SSp) {
    __shared__ float lsS[4][64], lsM[4][64], lsW[4][64];
    int b = blockIdx.x >> 4;
    int dg = blockIdx.x & 15;
    int wave = threadIdx.x >> 6, lane = threadIdx.x & 63;
    int d = dg * 64 + lane;
    size_t base = ((size_t)b * NCHUNK) * D_DIM + d;
    int c0 = wave * SEG;

    float O = 0.f, m = -3.4e38f;
    for (int j = 0; j < SEG; j++) {
        size_t ci = base + (size_t)(c0 + j) * D_DIM;
        m = fmaxf(m, O + Ml[ci]);
        O += S[ci];
    }
    lsS[wave][lane] = O; lsM[wave][lane] = m;
    __syncthreads();

    float myOsup = 0.f, gm = -3.4e38f;
    {
        float o = 0.f;
        #pragma unroll
        for (int w2 = 0; w2 < 4; w2++) {
            if (w2 == wave) myOsup = o;
            gm = fmaxf(gm, o + lsM[w2][lane]);
            o += lsS[w2][lane];
        }
    }

    float wv[SEG];
    float wacc = 0.f, Oc = myOsup;
    for (int j = 0; j < SEG; j++) {
        size_t ci = base + (size_t)(c0 + j) * D_DIM;
        Of[ci] = Oc - gm;
        float wcj = __expf(Oc + Ml[ci] - gm) * Tb[ci];
        wv[j] = wacc;
        wacc += wcj;
        Oc += S[ci];
    }
    lsW[wave][lane] = wacc;
    __syncthreads();

    float ssup = 0.f;
    #pragma unroll
    for (int w2 = 0; w2 < 4; w2++)
        if (w2 < wave) ssup += lsW[w2][lane];

    for (int j = 0; j < SEG; j++) {
        size_t ci = base + (size_t)(c0 + j) * D_DIM;
        SSp[ci] = ssup + wv[j];
    }
}

// pass 3: scale=exp(Of+p), s_star=SSp+local cumsum, out=s_star/(scale+1e-8) as bf16.
// osc aliases xn: la/xn reads at idx happen before osc write at idx, same thread.
__global__ __launch_bounds__(256) void scan_final(const u16* __restrict__ la,
                                                  const u16* __restrict__ xn,
                                                  const float* __restrict__ bs,
                                                  const float* __restrict__ Of,
                                                  const float* __restrict__ SSp,
                                                  u16* __restrict__ osc) {
    int bc = blockIdx.x;
    int b = bc >> 7, c = bc & (NCHUNK - 1);
    int d = blockIdx.y * 256 + threadIdx.x;
    float bsv = bs[0];
    size_t base = ((size_t)(b * T_DIM + c * CHUNK)) * D_DIM + d;
    size_t ci = ((size_t)(b * NCHUNK + c)) * D_DIM + d;
    float ofs = Of[ci], ss = SSp[ci], p = 0.f;
    #pragma unroll
    for (int t = 0; t < CHUNK; t++) {
        size_t idx = base + (size_t)t * D_DIM;
        float lav = bf2f(la[idx]);
        p += lav;
        float scv = __expf(ofs + p);
        float bx = bsv * (-expm1f(lav)) * bf2f(xn[idx]);
        ss += bx * scv;
        osc[idx] = f2bf(ss / (scv + 1e-8f));
    }
}

extern "C" void kernel_launch(void* const* d_in, const int* in_sizes, int n_in,
                              void* d_out, int out_size, void* d_ws, size_t ws_size,
                              hipStream_t stream) {
    const float* x   = (const float*)d_in[0];
    const float* lnw = (const float*)d_in[1];
    const float* lnb = (const float*)d_in[2];
    const float* Wf  = (const float*)d_in[3];
    const float* bf_ = (const float*)d_in[4];
    const float* Wr  = (const float*)d_in[5];
    const float* br  = (const float*)d_in[6];
    const float* ab  = (const float*)d_in[7];
    const float* bs  = (const float*)d_in[8];
    float* out = (float*)d_out;

    // workspace (78 MB):
    //   xn  : [ 0,32MB) bf16 layernorm out; later overwritten in-place by scan output
    //   la  : [32,64MB) bf16 log(alpha+1e-8) from GEMM1
    //   Wfc : [64,66MB) bf16 Wf     Wrc : [66,68MB) bf16 Wr
    //   S,Ml,Tb,Of,SSp : 5 x 2MB fp32 at [68,78MB)
    char* w = (char*)d_ws;
    u16* xn  = (u16*)w;
    u16* la  = (u16*)(w + (size_t)33554432);
    u16* Wfc = (u16*)(w + (size_t)67108864);
    u16* Wrc = (u16*)(w + (size_t)69206016);
    float* S   = (float*)(w + (size_t)71303168);
    float* Ml  = S  + 524288;
    float* Tb  = Ml + 524288;
    float* Of  = Tb + 524288;
    float* SSp = Of + 524288;
    u16* osc = xn;

    conv2_kernel<<<dim3(2048), dim3(256), 0, stream>>>(Wf, Wr, Wfc, Wrc);
    ln_kernel<<<dim3(M_DIM), dim3(256), 0, stream>>>(x, lnw, lnb, xn);
    gemm_kernel<0><<<dim3(D_DIM / 128, M_DIM / 128), dim3(256), 0, stream>>>(
        xn, Wfc, bf_, nullptr, ab, la, nullptr);
    scan_chunk<<<dim3(B_DIM * NCHUNK, 4), dim3(256), 0, stream>>>(la, xn, bs, S, Ml, Tb);
    scan_combine<<<dim3(B_DIM * 16), dim3(256), 0, stream>>>(S, Ml, Tb, Of, SSp);
    scan_final<<<dim3(B_DIM * NCHUNK, 4), dim3(256), 0, stream>>>(la, xn, bs, Of, SSp, osc);
    gemm_kernel<1><<<dim3(D_DIM / 128, M_DIM / 128), dim3(256), 0, stream>>>(
        osc, Wrc, br, x, nullptr, nullptr, out);
}